// Round 2
// baseline (2769.548 us; speedup 1.0000x reference)
//
#include <hip/hip_runtime.h>
#include <cstdint>

// CVFRLayer: x_{t+1} = (1-dt)x + dt*(nl(x) @ B) + sqrt(dt)*eps*(noise_t @ G^T)
// B = (A @ (I-P) + P)^T, P block-diagonal (16 blocks of 128, value pval).
// B[k,n] = A[n,k] - pval*rowblocksum(A,n,blk(k)) + pval*[blk(n)==blk(k)]
//   => B^T operand stored [N][K] comes from A's ROWS (cheap prep).
// KEY HOIST: noise[t] @ G^T is independent of the recurrence -> precompute
//   Z[t] = bf16( Nb[t] @ Gs ) for all t in ONE parallel 51200x2048x2048 GEMM.
// Sequential step then is only: x = (1-dt)x + Y@BTs + Z_t  (K=2048).

typedef unsigned short ushort_t;
typedef __bf16 bf16x8 __attribute__((ext_vector_type(8)));
typedef float f32x4 __attribute__((ext_vector_type(4)));
typedef unsigned short u16x4 __attribute__((ext_vector_type(4)));
typedef unsigned short u16x8 __attribute__((ext_vector_type(8)));

#define SZ 2048
#define BATCH 512
#define NSTEPS 100

static constexpr float DT = 0.03f;
static constexpr float GAM = 0.125f;
static constexpr float PVAL = (float)(1.0 / (128.0 + 2.2627416997969522e-07));
static constexpr float CNOISE = 0.017320508075688773f;  // sqrt(dt)*eps

__device__ __forceinline__ unsigned short f2bf(float f) {
    unsigned int u = __builtin_bit_cast(unsigned int, f);
    return (unsigned short)((u + 0x7fffu + ((u >> 16) & 1u)) >> 16);
}
__device__ __forceinline__ float bf2f(unsigned short h) {
    unsigned int u = ((unsigned int)h) << 16;
    return __builtin_bit_cast(float, u);
}
__device__ __forceinline__ void async16(const void* g, void* l) {
    __builtin_amdgcn_global_load_lds(
        (__attribute__((address_space(1))) void*)(uintptr_t)g,
        (__attribute__((address_space(3))) void*)(uint32_t)(uintptr_t)l,
        16, 0, 0);
}

// ---------- conv: noise f32 -> bf16 (whole trajectory, 400MB -> 200MB) ----------
__global__ __launch_bounds__(256) void conv_kernel(const float* __restrict__ n,
                                                   ushort_t* __restrict__ nb) {
    const size_t i = ((size_t)blockIdx.x * 256 + threadIdx.x) * 4;
    f32x4 v = *(const f32x4*)(n + i);
    u16x4 o;
#pragma unroll
    for (int e = 0; e < 4; ++e) o[e] = f2bf(v[e]);
    *(u16x4*)(nb + i) = o;
}

// ---------- prep: BTs (dt-scaled B^T rows) and Gs (cnoise-scaled G rows), bf16 ----------
__global__ __launch_bounds__(256) void prep_kernel(const float* __restrict__ A,
                                                   const float* __restrict__ G,
                                                   ushort_t* __restrict__ BTs,
                                                   ushort_t* __restrict__ Gs) {
    const int n = blockIdx.x;
    const int t = threadIdx.x;
    __shared__ float s16[16];
    const float* arow = A + (size_t)n * SZ;
    f32x4 a0 = *(const f32x4*)(arow + t * 8);
    f32x4 a1 = *(const f32x4*)(arow + t * 8 + 4);
    float ps = a0[0] + a0[1] + a0[2] + a0[3] + a1[0] + a1[1] + a1[2] + a1[3];
#pragma unroll
    for (int m = 1; m < 16; m <<= 1) ps += __shfl_xor(ps, m, 64);
    if ((t & 15) == 0) s16[t >> 4] = ps * PVAL;
    __syncthreads();
    const int seg = t >> 4;
    const float s = s16[seg];
    const float diag = (seg == (n >> 7)) ? PVAL : 0.0f;
    float av[8] = {a0[0], a0[1], a0[2], a0[3], a1[0], a1[1], a1[2], a1[3]};
    u16x8 ov;
#pragma unroll
    for (int i = 0; i < 8; ++i) ov[i] = f2bf(DT * (av[i] - s + diag));
    *(u16x8*)&BTs[(size_t)n * SZ + t * 8] = ov;

    const float* grow = G + (size_t)n * SZ;
    f32x4 g0 = *(const f32x4*)(grow + t * 8);
    f32x4 g1 = *(const f32x4*)(grow + t * 8 + 4);
    float gv[8] = {g0[0], g0[1], g0[2], g0[3], g1[0], g1[1], g1[2], g1[3]};
    u16x8 og;
#pragma unroll
    for (int i = 0; i < 8; ++i) og[i] = f2bf(CNOISE * gv[i]);
    *(u16x8*)&Gs[(size_t)n * SZ + t * 8] = og;
}

// ---------- init: xbuf = x, Y0 = bf16(nl(x)) ----------
__global__ __launch_bounds__(256) void init_kernel(const float* __restrict__ x,
                                                   float* __restrict__ xbuf,
                                                   ushort_t* __restrict__ Y0) {
    const size_t i = ((size_t)blockIdx.x * 256 + threadIdx.x) * 4;
    f32x4 xv = *(const f32x4*)(x + i);
    *(f32x4*)(xbuf + i) = xv;
    u16x4 yv;
#pragma unroll
    for (int e = 0; e < 4; ++e) {
        float x2 = xv[e] * xv[e];
        yv[e] = f2bf(x2 / (GAM + x2));
    }
    *(u16x4*)(Y0 + i) = yv;
}

// ---------- zgemm: Z = bf16(Nb @ Gs) ; M=51200, N=2048, K=2048 (m97-style) ----------
// 128x128 tile, 4 waves 2x2, BK=64, shared single-buffer LDS (32KB), XOR-swizzled.
__global__ __launch_bounds__(256) void zgemm_kernel(const ushort_t* __restrict__ Nb,
                                                    const ushort_t* __restrict__ Gs,
                                                    ushort_t* __restrict__ Z) {
    __shared__ ushort_t sm[16384];  // A: [0,16KB), B: [16KB,32KB)
    const int tid = threadIdx.x;
    const int w = tid >> 6, l = tid & 63;
    const int m0 = blockIdx.y << 7, n0 = blockIdx.x << 7;
    const char* Ag = (const char*)Nb + (size_t)m0 * 4096;
    const char* Bg = (const char*)Gs + (size_t)n0 * 4096;
    // staging slot s=i*256+tid: row=s>>3, p=s&7, global 16B-chunk q=p^(row&7)
    const int goff = (tid >> 3) * 4096 + (((tid & 7) ^ ((tid >> 3) & 7)) << 4);
    const int loff = tid * 16;
    const int lr = l & 15, q8 = l >> 4;
    const int wm = (w & 1) << 6, wn = (w >> 1) << 6;
    const int swz = lr & 7;
    f32x4 acc[4][4] = {};

    char* sA = (char*)sm;
    char* sB = sA + 16384;
    for (int kk = 0; kk < 32; ++kk) {
        __syncthreads();
        const char* Ac = Ag + kk * 128;
        const char* Bc = Bg + kk * 128;
#pragma unroll
        for (int i = 0; i < 4; ++i) {
            async16(Ac + i * 131072 + goff, sA + i * 4096 + loff);
            async16(Bc + i * 131072 + goff, sB + i * 4096 + loff);
        }
        asm volatile("s_waitcnt vmcnt(0)" ::: "memory");
        __syncthreads();
#pragma unroll
        for (int half = 0; half < 2; ++half) {
            const int qpos = ((((half << 2) | q8) ^ swz) << 4);
            bf16x8 af[4], bfv[4];
#pragma unroll
            for (int f = 0; f < 4; ++f) {
                af[f] = *(const bf16x8*)(sA + (wm + f * 16 + lr) * 128 + qpos);
                bfv[f] = *(const bf16x8*)(sB + (wn + f * 16 + lr) * 128 + qpos);
            }
#pragma unroll
            for (int fr = 0; fr < 4; ++fr)
#pragma unroll
                for (int fc = 0; fc < 4; ++fc)
                    acc[fr][fc] = __builtin_amdgcn_mfma_f32_16x16x32_bf16(
                        af[fr], bfv[fc], acc[fr][fc], 0, 0, 0);
        }
    }
    ushort_t* zr = Z + (size_t)m0 * SZ + n0;
#pragma unroll
    for (int fr = 0; fr < 4; ++fr)
#pragma unroll
        for (int reg = 0; reg < 4; ++reg) {
            const size_t rb = (size_t)(wm + fr * 16 + q8 * 4 + reg) * SZ;
#pragma unroll
            for (int fc = 0; fc < 4; ++fc)
                zr[rb + wn + fc * 16 + lr] = f2bf(acc[fr][fc][reg]);
        }
}

// ---------- step: C = Y@BTs (K=2048), x = (1-dt)x + C + Z_t ----------
// 512 threads = 8 waves, each owns K=256 (8 chunks of k=32) with wave-PRIVATE
// double-buffered LDS (128KB total) -> no barriers in K-loop, 2 waves/SIMD.
__global__ __launch_bounds__(512, 2) void step_kernel(
    const ushort_t* __restrict__ Ycur, const ushort_t* __restrict__ BTs,
    const ushort_t* __restrict__ Zt, const float* __restrict__ xin,
    float* __restrict__ xout, ushort_t* __restrict__ Ynext) {
    extern __shared__ ushort_t smem[];  // 128KB
    const int tid = threadIdx.x;
    const int w = tid >> 6, l = tid & 63;
    const int m0 = blockIdx.y << 6, n0 = blockIdx.x << 6;

    const char* Ag = (const char*)Ycur + (size_t)m0 * 4096 + w * 512;  // w*256 elems
    const char* Bg = (const char*)BTs + (size_t)n0 * 4096 + w * 512;
    char* waveLds = (char*)smem + w * 16384;  // 16KB/wave: 2 bufs x (A 4KB + B 4KB)

    // staging slot s=i*64+l: row=s>>2, p=s&3, global 16B-chunk q=p^((row>>1)&3)
    const int goffL = (l >> 2) * 4096 + ((((l & 3) ^ ((l >> 3) & 3))) << 4);
    const int loffL = l * 16;
    const int lr = l & 15, q8 = l >> 4;
    const int swz2 = (lr >> 1) & 3;

    f32x4 acc[4][4] = {};

    auto stage = [&](int ci, int b) {
        const char* Ac = Ag + ci * 64;
        const char* Bc = Bg + ci * 64;
        char* dA = waveLds + b * 8192;
        char* dB = dA + 4096;
#pragma unroll
        for (int i = 0; i < 4; ++i) {
            async16(Ac + i * 65536 + goffL, dA + i * 1024 + loffL);
            async16(Bc + i * 65536 + goffL, dB + i * 1024 + loffL);
        }
    };
    auto compute = [&](int b) {
        const char* TA = waveLds + b * 8192;
        const char* TB = TA + 4096;
        const int qpos = ((q8 ^ swz2) << 4);
        bf16x8 af[4], bfv[4];
#pragma unroll
        for (int f = 0; f < 4; ++f) {
            af[f] = *(const bf16x8*)(TA + (f * 16 + lr) * 64 + qpos);
            bfv[f] = *(const bf16x8*)(TB + (f * 16 + lr) * 64 + qpos);
        }
#pragma unroll
        for (int fr = 0; fr < 4; ++fr)
#pragma unroll
            for (int fc = 0; fc < 4; ++fc)
                acc[fr][fc] = __builtin_amdgcn_mfma_f32_16x16x32_bf16(
                    af[fr], bfv[fc], acc[fr][fc], 0, 0, 0);
    };

    stage(0, 0);
#pragma unroll 2
    for (int ci = 0; ci < 8; ++ci) {
        if (ci < 7) {
            stage(ci + 1, (ci + 1) & 1);
            asm volatile("s_waitcnt vmcnt(8)" ::: "memory");  // chunk ci drained
        } else {
            asm volatile("s_waitcnt vmcnt(0)" ::: "memory");
        }
        compute(ci & 1);
    }

    // 8-way K-split reduction, two phases of 32 output rows (69.6KB <= 128KB LDS)
    float* redF = (float*)smem;
#pragma unroll
    for (int p = 0; p < 2; ++p) {
        __syncthreads();
#pragma unroll
        for (int fl = 0; fl < 2; ++fl) {
            const int fr = p * 2 + fl;
            const int rl = fl * 16 + q8 * 4;
#pragma unroll
            for (int fc = 0; fc < 4; ++fc) {
                const int c = fc * 16 + lr;
#pragma unroll
                for (int reg = 0; reg < 4; ++reg)
                    redF[w * 2176 + (rl + reg) * 68 + c] = acc[fr][fc][reg];
            }
        }
        __syncthreads();
        {
            const int r = tid >> 4;            // 0..31
            const int c0 = (tid & 15) << 2;    // 0..60
            const int off = r * 68 + c0;
            f32x4 s = *(const f32x4*)&redF[off];
#pragma unroll
            for (int ww = 1; ww < 8; ++ww)
                s = s + *(const f32x4*)&redF[ww * 2176 + off];
            const size_t gb = (size_t)(m0 + p * 32 + r) * SZ + n0 + c0;
            f32x4 xv = *(const f32x4*)(xin + gb);
            u16x4 zb = *(const u16x4*)(Zt + gb);
            f32x4 xn;
#pragma unroll
            for (int e = 0; e < 4; ++e) xn[e] = xv[e] * (1.0f - DT) + s[e] + bf2f(zb[e]);
            *(f32x4*)(xout + gb) = xn;
            u16x4 yv;
#pragma unroll
            for (int e = 0; e < 4; ++e) {
                float x2 = xn[e] * xn[e];
                yv[e] = f2bf(x2 / (GAM + x2));
            }
            *(u16x4*)(Ynext + gb) = yv;
        }
    }
}

extern "C" void kernel_launch(void* const* d_in, const int* in_sizes, int n_in,
                              void* d_out, int out_size, void* d_ws, size_t ws_size,
                              hipStream_t stream) {
    const float* x = (const float*)d_in[0];
    const float* A = (const float*)d_in[1];
    const float* G = (const float*)d_in[2];
    const float* noise = (const float*)d_in[3];
    float* out = (float*)d_out;
    char* ws = (char*)d_ws;

    float* xbuf = (float*)(ws);                               // 4 MB
    ushort_t* Y0 = (ushort_t*)(ws + ((size_t)4 << 20));       // 2 MB
    ushort_t* Y1 = (ushort_t*)(ws + ((size_t)6 << 20));       // 2 MB
    ushort_t* BTs = (ushort_t*)(ws + ((size_t)8 << 20));      // 8 MB
    ushort_t* Gsc = (ushort_t*)(ws + ((size_t)16 << 20));     // 8 MB
    ushort_t* Nb = (ushort_t*)(ws + ((size_t)24 << 20));      // 209.7 MB
    ushort_t* Z = (ushort_t*)(ws + ((size_t)240 << 20));      // 209.7 MB (ends ~450MB)

    (void)hipFuncSetAttribute((const void*)step_kernel,
                              hipFuncAttributeMaxDynamicSharedMemorySize, 131072);

    conv_kernel<<<dim3(102400), dim3(256), 0, stream>>>(noise, Nb);
    prep_kernel<<<dim3(SZ), dim3(256), 0, stream>>>(A, G, BTs, Gsc);
    init_kernel<<<dim3(1024), dim3(256), 0, stream>>>(x, xbuf, Y0);
    zgemm_kernel<<<dim3(16, 400), dim3(256), 0, stream>>>(Nb, Gsc, Z);

    ushort_t* Yc = Y0;
    ushort_t* Yn = Y1;
    for (int t = 0; t < NSTEPS; ++t) {
        float* xo = (t == NSTEPS - 1) ? out : xbuf;
        step_kernel<<<dim3(32, 8), dim3(512), 131072, stream>>>(
            Yc, BTs, Z + (size_t)t * BATCH * SZ, xbuf, xo, Yn);
        ushort_t* tmp = Yc; Yc = Yn; Yn = tmp;
    }
}